// Round 1
// baseline (83.436 us; speedup 1.0000x reference)
//
#include <hip/hip_runtime.h>

// PackedAvgPool1d, kernel == stride == 2, H = 1024 (fixed by reference).
// Outputs (flat fp32, concatenated): y[new_total*H], new_seq_lens[B], new_cu[B+1].

#define HDIM 1024
#define ROW_VEC (HDIM / 4)   // 256 float4 per row

// Single-thread meta: new_len = ceil(L/2); prefix-sum into new_cu.
// Writes fp32 copies to the output tail and an int32 new_cu into workspace
// for the main kernel's row->segment lookup.
__global__ void pool_meta_kernel(const int* __restrict__ seq_lens, int B,
                                 float* __restrict__ out_lens,
                                 float* __restrict__ out_cu,
                                 int* __restrict__ ws_cu) {
    if (blockIdx.x == 0 && threadIdx.x == 0) {
        int acc = 0;
        ws_cu[0] = 0;
        out_cu[0] = 0.0f;
        for (int i = 0; i < B; ++i) {
            int L = seq_lens[i];
            int nl = (L + 1) >> 1;          // ceil(L/2)
            out_lens[i] = (float)nl;
            acc += nl;
            ws_cu[i + 1] = acc;
            out_cu[i + 1] = (float)acc;
        }
    }
}

// One block per output row; thread t handles float4 t of the row.
// Last row of an odd-length segment averages a single token (norm = 1).
__global__ __launch_bounds__(256) void pool_main_kernel(
    const float* __restrict__ x,
    const int* __restrict__ cu,        // input cumulative offsets (B+1, int32)
    const int* __restrict__ new_cu,    // output cumulative offsets (B+1, int32, in ws)
    int B,
    float* __restrict__ y) {
    const int r = blockIdx.x;

    // Uniform binary search: find b with new_cu[b] <= r < new_cu[b+1].
    int lo = 0, hi = B - 1;
    while (lo < hi) {
        int mid = (lo + hi + 1) >> 1;
        if (new_cu[mid] <= r) lo = mid; else hi = mid - 1;
    }
    const int b = lo;
    const int j = r - new_cu[b];
    const int base = cu[b];
    const int L = cu[b + 1] - base;
    const int i0 = base + 2 * j;

    const int t = threadIdx.x;  // 0..255
    const float4* row0 = (const float4*)(x + (size_t)i0 * HDIM);
    float4 v = row0[t];
    if (2 * j + 1 < L) {
        const float4* row1 = (const float4*)(x + (size_t)(i0 + 1) * HDIM);
        float4 w = row1[t];
        v.x = (v.x + w.x) * 0.5f;
        v.y = (v.y + w.y) * 0.5f;
        v.z = (v.z + w.z) * 0.5f;
        v.w = (v.w + w.w) * 0.5f;
    }
    float4* outrow = (float4*)(y + (size_t)r * HDIM);
    outrow[t] = v;
}

extern "C" void kernel_launch(void* const* d_in, const int* in_sizes, int n_in,
                              void* d_out, int out_size, void* d_ws, size_t ws_size,
                              hipStream_t stream) {
    const float* x        = (const float*)d_in[0];
    const int*   seq_lens = (const int*)d_in[1];
    const int*   cu       = (const int*)d_in[2];
    // d_in[3] = max_seq_len; general path handles max_seq_len==1 identically.

    const int B = in_sizes[1];                       // 64
    const int new_total = (out_size - (2 * B + 1)) / HDIM;

    float* y        = (float*)d_out;
    float* out_lens = y + (size_t)new_total * HDIM;
    float* out_cu   = out_lens + B;
    int*   ws_cu    = (int*)d_ws;                    // B+1 ints

    hipLaunchKernelGGL(pool_meta_kernel, dim3(1), dim3(64), 0, stream,
                       seq_lens, B, out_lens, out_cu, ws_cu);
    hipLaunchKernelGGL(pool_main_kernel, dim3(new_total), dim3(256), 0, stream,
                       x, cu, ws_cu, B, y);
}

// Round 2
// 80.627 us; speedup vs baseline: 1.0348x; 1.0348x over previous
//
#include <hip/hip_runtime.h>

// PackedAvgPool1d, kernel == stride == 2, H = 1024 (fixed by reference).
// Outputs (flat fp32, concatenated): y[new_total*H], new_seq_lens[B], new_cu[B+1].
//
// Single fused kernel: each wave rebuilds the B<=64 segment prefix sums
// in-register (coalesced seq_lens load + shfl_up scans), locates each output
// row's segment via ballot+popc, and streams 4 rows per block for MLP.

#define HDIM 1024
#define RPB  4      // output rows per block

__global__ __launch_bounds__(256) void pool_fused_kernel(
    const float* __restrict__ x,
    const int* __restrict__ seq_lens,
    int B, int new_total,
    float* __restrict__ y,
    float* __restrict__ out_lens,
    float* __restrict__ out_cu)
{
    const int tid  = threadIdx.x;
    const int lane = tid & 63;

    // --- per-wave segment table (B <= 64) ---
    int L  = (lane < B) ? seq_lens[lane] : 0;
    int nl = (L + 1) >> 1;            // new_len = ceil(L/2)
    int S = nl, C = L;                // inclusive scans of nl and L
    #pragma unroll
    for (int d = 1; d < 64; d <<= 1) {
        int s2 = __shfl_up(S, d, 64);
        int c2 = __shfl_up(C, d, 64);
        if (lane >= d) { S += s2; C += c2; }
    }

    // block 0, wave 0 writes the fp32 meta tail
    if (blockIdx.x == 0 && tid < 64) {
        if (lane < B) {
            out_lens[lane]   = (float)nl;
            out_cu[lane + 1] = (float)S;
        }
        if (lane == 0) out_cu[0] = 0.0f;
    }

    const int r0 = blockIdx.x * RPB;

    bool  valid[RPB], pair[RPB];
    float4 v0[RPB], v1[RPB];

    // phase 1: locate rows, issue all loads (independent -> overlapped)
    #pragma unroll
    for (int k = 0; k < RPB; ++k) {
        const int r = r0 + k;
        valid[k] = (r < new_total);
        const int rr = valid[k] ? r : 0;
        // segment b = #{i : S_i <= rr}  (rr is wave-uniform)
        const int b   = (int)__popcll(__ballot(S <= rr));
        const int Sb  = __shfl(S,  b, 64);
        const int nlb = __shfl(nl, b, 64);
        const int Cb  = __shfl(C,  b, 64);
        const int Lb  = __shfl(L,  b, 64);
        const int j   = rr - (Sb - nlb);       // row within segment
        const int i0  = (Cb - Lb) + 2 * j;     // input row index
        pair[k] = (2 * j + 1 < Lb);
        const float4* row0 = (const float4*)(x + (size_t)i0 * HDIM);
        if (valid[k]) {
            v0[k] = row0[tid];
            if (pair[k]) v1[k] = (row0 + (HDIM / 4))[tid];
        }
    }

    // phase 2: combine + store
    #pragma unroll
    for (int k = 0; k < RPB; ++k) {
        if (!valid[k]) continue;
        const int r = r0 + k;
        float4 v = v0[k];
        if (pair[k]) {
            const float4 w = v1[k];
            v.x = (v.x + w.x) * 0.5f;
            v.y = (v.y + w.y) * 0.5f;
            v.z = (v.z + w.z) * 0.5f;
            v.w = (v.w + w.w) * 0.5f;
        }
        ((float4*)(y + (size_t)r * HDIM))[tid] = v;
    }
}

extern "C" void kernel_launch(void* const* d_in, const int* in_sizes, int n_in,
                              void* d_out, int out_size, void* d_ws, size_t ws_size,
                              hipStream_t stream) {
    const float* x        = (const float*)d_in[0];
    const int*   seq_lens = (const int*)d_in[1];
    // d_in[2] = cu_seq_lens (recomputed in-wave), d_in[3] = max_seq_len
    // (general path is exact for max_seq_len==1 too).

    const int B = in_sizes[1];                       // 64 (<= wave width)
    const int new_total = (out_size - (2 * B + 1)) / HDIM;

    float* y        = (float*)d_out;
    float* out_lens = y + (size_t)new_total * HDIM;
    float* out_cu   = out_lens + B;

    const int grid = (new_total + RPB - 1) / RPB;
    hipLaunchKernelGGL(pool_fused_kernel, dim3(grid), dim3(256), 0, stream,
                       x, seq_lens, B, new_total, y, out_lens, out_cu);
}

// Round 3
// 79.006 us; speedup vs baseline: 1.0561x; 1.0205x over previous
//
#include <hip/hip_runtime.h>

// PackedAvgPool1d, kernel == stride == 2, H = 1024 (fixed by reference).
// Outputs (flat fp32, concatenated): y[new_total*H], new_seq_lens[B], new_cu[B+1].
//
// Persistent grid-stride kernel: segment prefix sums built once per block
// in-register (B <= 64: coalesced seq_lens load + shfl_up scans), rows
// located via ballot+popc, nontemporal float4 streaming (zero reuse).

#define HDIM 1024
#define RPB  4      // output rows per loop iteration

typedef __attribute__((ext_vector_type(4))) float f4;

__global__ __launch_bounds__(256) void pool_fused_kernel(
    const float* __restrict__ x,
    const int* __restrict__ seq_lens,
    int B, int new_total,
    float* __restrict__ y,
    float* __restrict__ out_lens,
    float* __restrict__ out_cu)
{
    const int tid  = threadIdx.x;
    const int lane = tid & 63;

    // --- per-wave segment table (B <= 64) ---
    int L  = (lane < B) ? seq_lens[lane] : 0;
    int nl = (L + 1) >> 1;            // new_len = ceil(L/2)
    int S = nl, C = L;                // inclusive scans of nl and L
    #pragma unroll
    for (int d = 1; d < 64; d <<= 1) {
        int s2 = __shfl_up(S, d, 64);
        int c2 = __shfl_up(C, d, 64);
        if (lane >= d) { S += s2; C += c2; }
    }

    // block 0, wave 0 writes the fp32 meta tail
    if (blockIdx.x == 0 && tid < 64) {
        if (lane < B) {
            out_lens[lane]   = (float)nl;
            out_cu[lane + 1] = (float)S;
        }
        if (lane == 0) out_cu[0] = 0.0f;
    }

    const int ngroups = (new_total + RPB - 1) / RPB;

    for (int g = blockIdx.x; g < ngroups; g += gridDim.x) {
        const int r0 = g * RPB;

        bool valid[RPB], pair[RPB];
        f4 v0[RPB], v1[RPB];

        // phase 1: locate rows, issue all loads (independent -> overlapped)
        #pragma unroll
        for (int k = 0; k < RPB; ++k) {
            const int r = r0 + k;
            valid[k] = (r < new_total);
            const int rr = valid[k] ? r : 0;
            // segment b = #{i : S_i <= rr}  (rr is wave-uniform)
            const int b   = (int)__popcll(__ballot(S <= rr));
            const int Sb  = __shfl(S,  b, 64);
            const int nlb = __shfl(nl, b, 64);
            const int Cb  = __shfl(C,  b, 64);
            const int Lb  = __shfl(L,  b, 64);
            const int j   = rr - (Sb - nlb);       // row within segment
            const int i0  = (Cb - Lb) + 2 * j;     // input row index
            pair[k] = (2 * j + 1 < Lb);
            const f4* row0 = (const f4*)(x + (size_t)i0 * HDIM);
            if (valid[k]) {
                v0[k] = __builtin_nontemporal_load(row0 + tid);
                if (pair[k]) v1[k] = __builtin_nontemporal_load(row0 + (HDIM / 4) + tid);
            }
        }

        // phase 2: combine + store
        #pragma unroll
        for (int k = 0; k < RPB; ++k) {
            if (!valid[k]) continue;
            const int r = r0 + k;
            f4 v = v0[k];
            if (pair[k]) v = (v + v1[k]) * 0.5f;
            __builtin_nontemporal_store(v, (f4*)(y + (size_t)r * HDIM) + tid);
        }
    }
}

extern "C" void kernel_launch(void* const* d_in, const int* in_sizes, int n_in,
                              void* d_out, int out_size, void* d_ws, size_t ws_size,
                              hipStream_t stream) {
    const float* x        = (const float*)d_in[0];
    const int*   seq_lens = (const int*)d_in[1];
    // d_in[2] = cu_seq_lens (recomputed in-wave), d_in[3] = max_seq_len
    // (general path is exact for max_seq_len==1 too).

    const int B = in_sizes[1];                       // 64 (<= wave width)
    const int new_total = (out_size - (2 * B + 1)) / HDIM;

    float* y        = (float*)d_out;
    float* out_lens = y + (size_t)new_total * HDIM;
    float* out_cu   = out_lens + B;

    const int ngroups = (new_total + RPB - 1) / RPB;
    const int grid = ngroups < 2048 ? ngroups : 2048;
    hipLaunchKernelGGL(pool_fused_kernel, dim3(grid), dim3(256), 0, stream,
                       x, seq_lens, B, new_total, y, out_lens, out_cu);
}

// Round 4
// 70.051 us; speedup vs baseline: 1.1911x; 1.1278x over previous
//
#include <hip/hip_runtime.h>

// PackedAvgPool1d, kernel == stride == 2, H = 1024 (fixed by reference).
// Outputs (flat fp32, concatenated): y[new_total*H], new_seq_lens[B], new_cu[B+1].
//
// Persistent kernel, ONE OUTPUT ROW PER WAVE: each wave streams its row pair
// as 8 sequential 1KB loads from a single base (immediate-offset folding),
// combines, and writes 4KB sequentially. Segment table (B <= 64) rebuilt
// in-register per block: coalesced seq_lens load + shfl_up scans; row ->
// segment via ballot+popc. Nontemporal float4 (zero reuse).

#define HDIM 1024
#define F4_PER_ROW 256   // HDIM/4
#define RPG 4            // rows per group = waves per block

typedef __attribute__((ext_vector_type(4))) float f4;

__global__ __launch_bounds__(256) void pool_fused_kernel(
    const f4* __restrict__ xv,
    const int* __restrict__ seq_lens,
    int B, int new_total,
    f4* __restrict__ yv,
    float* __restrict__ out_lens,
    float* __restrict__ out_cu)
{
    const int tid  = threadIdx.x;
    const int lane = tid & 63;
    const int wid  = tid >> 6;     // wave id 0..3

    // --- per-wave segment table (B <= 64) ---
    int L  = (lane < B) ? seq_lens[lane] : 0;
    int nl = (L + 1) >> 1;            // new_len = ceil(L/2)
    int S = nl, C = L;                // inclusive scans of nl and L
    #pragma unroll
    for (int d = 1; d < 64; d <<= 1) {
        int s2 = __shfl_up(S, d, 64);
        int c2 = __shfl_up(C, d, 64);
        if (lane >= d) { S += s2; C += c2; }
    }

    // block 0, wave 0 writes the fp32 meta tail
    if (blockIdx.x == 0 && tid < 64) {
        if (lane < B) {
            out_lens[lane]   = (float)nl;
            out_cu[lane + 1] = (float)S;
        }
        if (lane == 0) out_cu[0] = 0.0f;
    }

    const int ngroups = (new_total + RPG - 1) / RPG;

    for (int g = blockIdx.x; g < ngroups; g += gridDim.x) {
        const int r = g * RPG + wid;      // this wave's output row
        if (r >= new_total) continue;     // wave-uniform

        // segment b = #{i : S_i <= r}   (r is wave-uniform)
        const int b   = (int)__popcll(__ballot(S <= r));
        const int Sb  = __shfl(S,  b, 64);
        const int nlb = __shfl(nl, b, 64);
        const int Cb  = __shfl(C,  b, 64);
        const int Lb  = __shfl(L,  b, 64);
        const int j   = r - (Sb - nlb);        // row within segment
        const int i0  = (Cb - Lb) + 2 * j;     // input row index
        const bool pr = (2 * j + 1 < Lb);      // has second token (uniform)

        // sequential 8KB read off one base; offsets fold to immediates
        const f4* r0 = xv + (size_t)i0 * F4_PER_ROW + lane;
        f4 v0[4], v1[4];
        #pragma unroll
        for (int c = 0; c < 4; ++c)
            v0[c] = __builtin_nontemporal_load(r0 + c * 64);
        if (pr) {
            #pragma unroll
            for (int c = 0; c < 4; ++c)
                v1[c] = __builtin_nontemporal_load(r0 + F4_PER_ROW + c * 64);
            #pragma unroll
            for (int c = 0; c < 4; ++c)
                v0[c] = (v0[c] + v1[c]) * 0.5f;
        }

        // sequential 4KB write
        f4* o = yv + (size_t)r * F4_PER_ROW + lane;
        #pragma unroll
        for (int c = 0; c < 4; ++c)
            __builtin_nontemporal_store(v0[c], o + c * 64);
    }
}

extern "C" void kernel_launch(void* const* d_in, const int* in_sizes, int n_in,
                              void* d_out, int out_size, void* d_ws, size_t ws_size,
                              hipStream_t stream) {
    const f4*  xv       = (const f4*)d_in[0];
    const int* seq_lens = (const int*)d_in[1];
    // d_in[2] = cu_seq_lens (recomputed in-wave), d_in[3] = max_seq_len
    // (general path is exact for max_seq_len==1 too).

    const int B = in_sizes[1];                       // 64 (<= wave width)
    const int new_total = (out_size - (2 * B + 1)) / HDIM;

    float* y        = (float*)d_out;
    float* out_lens = y + (size_t)new_total * HDIM;
    float* out_cu   = out_lens + B;

    const int ngroups = (new_total + RPG - 1) / RPG;
    const int grid = ngroups < 2048 ? ngroups : 2048;
    hipLaunchKernelGGL(pool_fused_kernel, dim3(grid), dim3(256), 0, stream,
                       xv, seq_lens, B, new_total, (f4*)y, out_lens, out_cu);
}